// Round 6
// baseline (1428.793 us; speedup 1.0000x reference)
//
#include <hip/hip_runtime.h>

#define TLEN  1024
#define HN    64
#define NB    4            // batch elements per block
#define KAUG  96           // 64 h + 4 x + 1 bias + 27 zero-pad
#define BROW  104          // h2 row stride in f16 (16B-aligned, conflict-benign)
#define LOG2E 1.4426950408889634f

typedef _Float16 v8h __attribute__((ext_vector_type(8)));
typedef float    v4f __attribute__((ext_vector_type(4)));

// MFMA LSTM: 256 blocks x 4 waves. Block owns 4 batch elems; wave w owns gate
// w (rows 64w..64w+64 of the 256-row gate matrix) => wave-uniform activation.
// Augmented K: A = [W_hh | W_ih | b_ih+b_hh | 0] (256 x 96) held as 12 f16
// MFMA A-frags (48 VGPR/lane, wave-shared -- ends the R1-R5 per-lane weight
// replication war at VGPR 92-152 spills). B = [h; x_t; 1; 0] staged in LDS
// as h2[n=16][BROW] f16. Per step/wave: 3 ds_read_b128 B-frags + 12
// v_mfma_f32_16x16x32_f16 + activation on C + LDS gate exchange; update
// thread (u,b') keeps c in a register, writes h back as f16, shuffle-reduces
// the FC output. log2e pre-folded into A (2*log2e for tanh gate).
// Layouts (guide-verified): A[m=lane&15][k=(lane>>4)*8+j],
// B[n=lane&15][k=(lane>>4)*8+j], C col=lane&15, row=(lane>>4)*4+reg.
__global__ __launch_bounds__(256, 1)
void lstm_mfma(const float* __restrict__ x,      // [B, T, 4]
               const float* __restrict__ W_ih,   // [256, 4]
               const float* __restrict__ W_hh,   // [256, 64]
               const float* __restrict__ b_ih,   // [256]
               const float* __restrict__ b_hh,   // [256]
               const float* __restrict__ W_fc,   // [1, 64]
               const float* __restrict__ b_fc,   // [1]
               float* __restrict__ out)          // [B, T]
{
    const int tid  = threadIdx.x;
    const int w    = tid >> 6;        // wave = gate (i,f,g,o) AND batch-in-block
    const int lane = tid & 63;
    const int quad = lane >> 4;
    const int col  = lane & 15;       // C col / B n
    const int u    = lane;            // update phase: hidden unit (0..63)
    const int b0   = blockIdx.x * NB;

    __shared__ __align__(16) _Float16 h2[16 * BROW];      // B staging [n][k]
    __shared__ __align__(16) float gates_s[HN * 16];      // [u][b'][gate]

    // ---- one-time: build A-fragments (f16, gate-scale pre-folded) ----
    const float s = (w == 2) ? 2.0f * LOG2E : LOG2E;      // tanh gate doubled
    v8h a00, a01, a02, a10, a11, a12, a20, a21, a22, a30, a31, a32;
#define LOADA(dst, T, C) { \
        int row = 64 * w + (T) * 16 + col; \
        _Pragma("unroll") \
        for (int j = 0; j < 8; ++j) { \
            int k = (C) * 32 + quad * 8 + j; \
            float v; \
            if (k < 64)      v = W_hh[row * 64 + k]; \
            else if (k < 68) v = W_ih[row * 4 + (k - 64)]; \
            else if (k == 68) v = b_ih[row] + b_hh[row]; \
            else             v = 0.0f; \
            dst[j] = (_Float16)(v * s); \
        } }
    LOADA(a00, 0, 0) LOADA(a01, 0, 1) LOADA(a02, 0, 2)
    LOADA(a10, 1, 0) LOADA(a11, 1, 1) LOADA(a12, 1, 2)
    LOADA(a20, 2, 0) LOADA(a21, 2, 1) LOADA(a22, 2, 2)
    LOADA(a30, 3, 0) LOADA(a31, 3, 1) LOADA(a32, 3, 2)
#undef LOADA

    const float wfc = W_fc[u];
    const float bfc = b_fc[0];

    // ---- init LDS: zero h2 (h=0, garbage cols 4..15 = 0), x_0, bias-one ----
    for (int i = tid; i < (16 * BROW) / 2; i += 256)
        ((unsigned int*)h2)[i] = 0u;
    __syncthreads();
    if (u < 4)                         // x columns k=64..67 for t=0
        h2[w * BROW + 64 + u] = (_Float16)x[((size_t)(b0 + w)) * TLEN * 4 + u];
    if (u == 4)                        // bias column k=68
        h2[w * BROW + 68] = (_Float16)1.0f;
    __syncthreads();

    float c_st = 0.0f;                 // c for (unit u, batch w) -- register

    for (int t = 0; t < TLEN; ++t) {
        // prefetch next x (consumed in update phase, ~200+ cyc later)
        int tn = (t + 1 < TLEN) ? t + 1 : TLEN - 1;
        float xv = 0.0f;
        if (u < 4)
            xv = x[((size_t)(b0 + w)) * TLEN * 4 + (size_t)tn * 4 + u];

        // ---- Phase 1: B-frags + 12 MFMA ----
        const v8h bf0 = *(const v8h*)(h2 + col * BROW +  0 + quad * 8);
        const v8h bf1 = *(const v8h*)(h2 + col * BROW + 32 + quad * 8);
        const v8h bf2 = *(const v8h*)(h2 + col * BROW + 64 + quad * 8);

        v4f acc0 = {0.f, 0.f, 0.f, 0.f}, acc1 = {0.f, 0.f, 0.f, 0.f};
        v4f acc2 = {0.f, 0.f, 0.f, 0.f}, acc3 = {0.f, 0.f, 0.f, 0.f};
        acc0 = __builtin_amdgcn_mfma_f32_16x16x32_f16(a00, bf0, acc0, 0, 0, 0);
        acc0 = __builtin_amdgcn_mfma_f32_16x16x32_f16(a01, bf1, acc0, 0, 0, 0);
        acc0 = __builtin_amdgcn_mfma_f32_16x16x32_f16(a02, bf2, acc0, 0, 0, 0);
        acc1 = __builtin_amdgcn_mfma_f32_16x16x32_f16(a10, bf0, acc1, 0, 0, 0);
        acc1 = __builtin_amdgcn_mfma_f32_16x16x32_f16(a11, bf1, acc1, 0, 0, 0);
        acc1 = __builtin_amdgcn_mfma_f32_16x16x32_f16(a12, bf2, acc1, 0, 0, 0);
        acc2 = __builtin_amdgcn_mfma_f32_16x16x32_f16(a20, bf0, acc2, 0, 0, 0);
        acc2 = __builtin_amdgcn_mfma_f32_16x16x32_f16(a21, bf1, acc2, 0, 0, 0);
        acc2 = __builtin_amdgcn_mfma_f32_16x16x32_f16(a22, bf2, acc2, 0, 0, 0);
        acc3 = __builtin_amdgcn_mfma_f32_16x16x32_f16(a30, bf0, acc3, 0, 0, 0);
        acc3 = __builtin_amdgcn_mfma_f32_16x16x32_f16(a31, bf1, acc3, 0, 0, 0);
        acc3 = __builtin_amdgcn_mfma_f32_16x16x32_f16(a32, bf2, acc3, 0, 0, 0);

        // ---- activation (wave-uniform fn) + scatter valid cols to LDS ----
        // C: row_in_tile = quad*4 + reg, col = lane&15; valid cols = 0..3
#define ACT(a) ((w == 2) \
        ? (1.0f - 2.0f * __builtin_amdgcn_rcpf(1.0f + __builtin_amdgcn_exp2f(a))) \
        : __builtin_amdgcn_rcpf(1.0f + __builtin_amdgcn_exp2f(-(a))))
        if (col < NB) {
            int ub = quad * 4;                       // row base within gate
#define STORE_TILE(acc, T) { \
            gates_s[((T)*16 + ub + 0) * 16 + col * 4 + w] = ACT(acc[0]); \
            gates_s[((T)*16 + ub + 1) * 16 + col * 4 + w] = ACT(acc[1]); \
            gates_s[((T)*16 + ub + 2) * 16 + col * 4 + w] = ACT(acc[2]); \
            gates_s[((T)*16 + ub + 3) * 16 + col * 4 + w] = ACT(acc[3]); }
            STORE_TILE(acc0, 0)
            STORE_TILE(acc1, 1)
            STORE_TILE(acc2, 2)
            STORE_TILE(acc3, 3)
#undef STORE_TILE
        }
#undef ACT
        __syncthreads();

        // ---- Phase 2: update (u, b'=w); c in register ----
        v4f gv = *(const v4f*)(gates_s + u * 16 + w * 4);   // i,f,g,o
        c_st = gv[1] * c_st + gv[0] * gv[2];
        float th = 1.0f - 2.0f * __builtin_amdgcn_rcpf(
                       1.0f + __builtin_amdgcn_exp2f(c_st * (2.0f * LOG2E)));
        float h = gv[3] * th;
        h2[w * BROW + u] = (_Float16)h;          // B k-column for next step
        if (u < 4)
            h2[w * BROW + 64 + u] = (_Float16)xv;  // x_{t+1}

        // FC: out[b0+w, t] = sum_u h*wfc + bfc (wave shuffle reduction)
        float p = h * wfc;
#pragma unroll
        for (int off = 32; off > 0; off >>= 1)
            p += __shfl_down(p, off, 64);
        if (u == 0)
            out[((size_t)(b0 + w)) * TLEN + t] = p + bfc;

        __syncthreads();
    }
}

extern "C" void kernel_launch(void* const* d_in, const int* in_sizes, int n_in,
                              void* d_out, int out_size, void* d_ws, size_t ws_size,
                              hipStream_t stream) {
    const float* x    = (const float*)d_in[0];
    const float* W_ih = (const float*)d_in[1];
    const float* W_hh = (const float*)d_in[2];
    const float* b_ih = (const float*)d_in[3];
    const float* b_hh = (const float*)d_in[4];
    const float* W_fc = (const float*)d_in[5];
    const float* b_fc = (const float*)d_in[6];
    float* out = (float*)d_out;

    const int B = in_sizes[0] / (TLEN * 4);   // 1024
    lstm_mfma<<<dim3(B / NB), dim3(256), 0, stream>>>(
        x, W_ih, W_hh, b_ih, b_hh, W_fc, b_fc, out);
}

// Round 8
// 740.519 us; speedup vs baseline: 1.9294x; 1.9294x over previous
//
#include <hip/hip_runtime.h>

#define TLEN  1024
#define HN    64
#define LOG2E 1.4426950408889634f

// clang builtins (__builtin_amdgcn_cvt_pkrtz / fdot2) use __fp16 vectors,
// NOT _Float16 -- R7 failed to compile on exactly that.
typedef __fp16 half2v __attribute__((ext_vector_type(2)));

// One wave (64 lanes) per batch element; 1024 blocks x 64 thr = 1 wave/SIMD
// exactly. Lane g owns hidden unit g's four gate rows (torch i,f,g,o) as
// PACKED f16 pairs {w[j], w[j+32]}: 128 half2 = 128 VGPRs (~170 live < the
// 256 addressable-VGPR limit that forced R4's spill; R6 proved f16 weights/h
// give absmax ~1e-3, well under threshold). v_dot2_f32_f16 = 2 MACs/instr,
// fp32 accumulate. h broadcast: hp = cvt_pkrtz(h, shfl_down(h,32)) -> lane j
// holds {h[j],h[j+32]}; 32 readlanes feed 128 dot2. NO barriers, NO LDS in
// the recurrence. x.W_ih as 2 dot2/gate (x packed f16 per step). log2e
// pre-folded into all weights/biases (2*log2e for the tanh gate).
// FC: h*wfc -> ring[64][65] (bank-free), transposed reduce + coalesced
// 64-wide store every 64 steps.

#define FOR32(X) \
    X(0) X(1) X(2) X(3) X(4) X(5) X(6) X(7) \
    X(8) X(9) X(10) X(11) X(12) X(13) X(14) X(15) \
    X(16) X(17) X(18) X(19) X(20) X(21) X(22) X(23) \
    X(24) X(25) X(26) X(27) X(28) X(29) X(30) X(31)

__global__ __launch_bounds__(64, 1)
void lstm_dot2(const float* __restrict__ x,      // [B, T, 4]
               const float* __restrict__ W_ih,   // [256, 4]
               const float* __restrict__ W_hh,   // [256, 64]
               const float* __restrict__ b_ih,   // [256]
               const float* __restrict__ b_hh,   // [256]
               const float* __restrict__ W_fc,   // [1, 64]
               const float* __restrict__ b_fc,   // [1]
               float* __restrict__ out)          // [B, T]
{
    const int b = blockIdx.x;
    const int g = threadIdx.x;   // hidden unit 0..63

    __shared__ float ring[64][65];   // FC partials, stride-65: conflict-free

    const float* wr_i = W_hh + (0 * HN + g) * HN;
    const float* wr_f = W_hh + (1 * HN + g) * HN;
    const float* wr_g = W_hh + (2 * HN + g) * HN;
    const float* wr_o = W_hh + (3 * HN + g) * HN;

    // ---- 128 named half2 weight pairs, pre-scaled, pinned ----
#define DECL(j) half2v pi##j, pf##j, pg##j, po##j;
    FOR32(DECL)
#undef DECL

#define LOADW(j) \
    pi##j = __builtin_amdgcn_cvt_pkrtz(wr_i[j] * LOG2E, wr_i[(j) + 32] * LOG2E); \
    pf##j = __builtin_amdgcn_cvt_pkrtz(wr_f[j] * LOG2E, wr_f[(j) + 32] * LOG2E); \
    pg##j = __builtin_amdgcn_cvt_pkrtz(wr_g[j] * (2.0f * LOG2E), \
                                       wr_g[(j) + 32] * (2.0f * LOG2E)); \
    po##j = __builtin_amdgcn_cvt_pkrtz(wr_o[j] * LOG2E, wr_o[(j) + 32] * LOG2E); \
    asm volatile("" : "+v"(pi##j), "+v"(pf##j), "+v"(pg##j), "+v"(po##j));
    FOR32(LOADW)
#undef LOADW

    // x-weights as f16 pairs (pre-scaled): 2 half2 per gate
    half2v wip0 = __builtin_amdgcn_cvt_pkrtz(W_ih[(0 * HN + g) * 4 + 0] * LOG2E,
                                             W_ih[(0 * HN + g) * 4 + 1] * LOG2E);
    half2v wip1 = __builtin_amdgcn_cvt_pkrtz(W_ih[(0 * HN + g) * 4 + 2] * LOG2E,
                                             W_ih[(0 * HN + g) * 4 + 3] * LOG2E);
    half2v wfp0 = __builtin_amdgcn_cvt_pkrtz(W_ih[(1 * HN + g) * 4 + 0] * LOG2E,
                                             W_ih[(1 * HN + g) * 4 + 1] * LOG2E);
    half2v wfp1 = __builtin_amdgcn_cvt_pkrtz(W_ih[(1 * HN + g) * 4 + 2] * LOG2E,
                                             W_ih[(1 * HN + g) * 4 + 3] * LOG2E);
    half2v wgp0 = __builtin_amdgcn_cvt_pkrtz(W_ih[(2 * HN + g) * 4 + 0] * 2.0f * LOG2E,
                                             W_ih[(2 * HN + g) * 4 + 1] * 2.0f * LOG2E);
    half2v wgp1 = __builtin_amdgcn_cvt_pkrtz(W_ih[(2 * HN + g) * 4 + 2] * 2.0f * LOG2E,
                                             W_ih[(2 * HN + g) * 4 + 3] * 2.0f * LOG2E);
    half2v wop0 = __builtin_amdgcn_cvt_pkrtz(W_ih[(3 * HN + g) * 4 + 0] * LOG2E,
                                             W_ih[(3 * HN + g) * 4 + 1] * LOG2E);
    half2v wop1 = __builtin_amdgcn_cvt_pkrtz(W_ih[(3 * HN + g) * 4 + 2] * LOG2E,
                                             W_ih[(3 * HN + g) * 4 + 3] * LOG2E);

    const float bias_i = (b_ih[0 * HN + g] + b_hh[0 * HN + g]) * LOG2E;
    const float bias_f = (b_ih[1 * HN + g] + b_hh[1 * HN + g]) * LOG2E;
    const float bias_g = (b_ih[2 * HN + g] + b_hh[2 * HN + g]) * (2.0f * LOG2E);
    const float bias_o = (b_ih[3 * HN + g] + b_hh[3 * HN + g]) * LOG2E;
    const float wfc = W_fc[g];
    const float bfc = b_fc[0];

    const float* xb = x   + (size_t)b * TLEN * 4;
    float*       ob = out + (size_t)b * TLEN;

    float h = 0.0f, c = 0.0f;
    int hp = 0;   // packed h pair {h[j], h[j+32]} per lane (start: h=0)

    float4 x0 = *(const float4*)(xb);
    half2v xp0 = __builtin_amdgcn_cvt_pkrtz(x0.x, x0.y);
    half2v xp1 = __builtin_amdgcn_cvt_pkrtz(x0.z, x0.w);

    for (int t = 0; t < TLEN; ++t) {
        int tn = t + 1; if (tn >= TLEN) tn = TLEN - 1;
        float4 xn = *(const float4*)(xb + (size_t)tn * 4);   // prefetch

        // ---- gate accumulators: bias + x.W_ih (2 dot2 each) ----
        float ai = __builtin_amdgcn_fdot2(wip0, xp0, bias_i, false);
        float af = __builtin_amdgcn_fdot2(wfp0, xp0, bias_f, false);
        float ag = __builtin_amdgcn_fdot2(wgp0, xp0, bias_g, false);
        float ao = __builtin_amdgcn_fdot2(wop0, xp0, bias_o, false);
        ai = __builtin_amdgcn_fdot2(wip1, xp1, ai, false);
        af = __builtin_amdgcn_fdot2(wfp1, xp1, af, false);
        ag = __builtin_amdgcn_fdot2(wgp1, xp1, ag, false);
        ao = __builtin_amdgcn_fdot2(wop1, xp1, ao, false);

        // ---- hh matvec: 32 readlanes x 4 dot2 (pairs {j, j+32}) ----
#define MAC(j) { \
        int hj = __builtin_amdgcn_readlane(hp, j); \
        half2v hh = __builtin_bit_cast(half2v, hj); \
        ai = __builtin_amdgcn_fdot2(pi##j, hh, ai, false); \
        af = __builtin_amdgcn_fdot2(pf##j, hh, af, false); \
        ag = __builtin_amdgcn_fdot2(pg##j, hh, ag, false); \
        ao = __builtin_amdgcn_fdot2(po##j, hh, ao, false); }
        FOR32(MAC)
#undef MAC

        // ---- activations (pre-scaled): sigmoid/tanh via exp2+rcp ----
        float si = __builtin_amdgcn_rcpf(1.0f + __builtin_amdgcn_exp2f(-ai));
        float sf = __builtin_amdgcn_rcpf(1.0f + __builtin_amdgcn_exp2f(-af));
        float tg = 1.0f - 2.0f * __builtin_amdgcn_rcpf(
                                     1.0f + __builtin_amdgcn_exp2f(ag));
        float so = __builtin_amdgcn_rcpf(1.0f + __builtin_amdgcn_exp2f(-ao));

        c = sf * c + si * tg;
        float th = 1.0f - 2.0f * __builtin_amdgcn_rcpf(
                       1.0f + __builtin_amdgcn_exp2f(c * (2.0f * LOG2E)));
        h = so * th;

        // repack h pairs for next step's readlane broadcast
        float h_hi = __shfl_down(h, 32, 64);
        hp = __builtin_bit_cast(int, __builtin_amdgcn_cvt_pkrtz(h, h_hi));

        // repack next x
        xp0 = __builtin_amdgcn_cvt_pkrtz(xn.x, xn.y);
        xp1 = __builtin_amdgcn_cvt_pkrtz(xn.z, xn.w);

        // ---- FC ring + periodic coalesced store ----
        ring[t & 63][g] = h * wfc;
        if ((t & 63) == 63) {
            __syncthreads();   // single wave: just orders LDS w->r
            float s0 = 0.f, s1 = 0.f, s2 = 0.f, s3 = 0.f;
#pragma unroll
            for (int k = 0; k < HN; k += 4) {
                s0 += ring[g][k];
                s1 += ring[g][k + 1];
                s2 += ring[g][k + 2];
                s3 += ring[g][k + 3];
            }
            ob[(t - 63) + g] = (s0 + s1) + (s2 + s3) + bfc;
        }
    }
}

extern "C" void kernel_launch(void* const* d_in, const int* in_sizes, int n_in,
                              void* d_out, int out_size, void* d_ws, size_t ws_size,
                              hipStream_t stream) {
    const float* x    = (const float*)d_in[0];
    const float* W_ih = (const float*)d_in[1];
    const float* W_hh = (const float*)d_in[2];
    const float* b_ih = (const float*)d_in[3];
    const float* b_hh = (const float*)d_in[4];
    const float* W_fc = (const float*)d_in[5];
    const float* b_fc = (const float*)d_in[6];
    float* out = (float*)d_out;

    const int B = in_sizes[0] / (TLEN * 4);   // 1024
    lstm_dot2<<<dim3(B), dim3(64), 0, stream>>>(
        x, W_ih, W_hh, b_ih, b_hh, W_fc, b_fc, out);
}